// Round 8
// baseline (401.905 us; speedup 1.0000x reference)
//
#include <hip/hip_runtime.h>

#define TSTEPS 1024
#define CH 4               // chains per SET; replicated 4x across MFMA m-rows
#define SETS 2             // two independent chain-sets per workgroup

typedef _Float16 half8  __attribute__((ext_vector_type(8)));
typedef float    f32x4  __attribute__((ext_vector_type(4)));

#define MFMA16(A_, B_, C_) __builtin_amdgcn_mfma_f32_16x16x32_f16((A_), (B_), (C_), 0, 0, 0)

__device__ __forceinline__ float fast_rcp(float x) { return __builtin_amdgcn_rcpf(x); }
__device__ __forceinline__ float fast_exp2(float x) {
#if __has_builtin(__builtin_amdgcn_exp2f)
    return __builtin_amdgcn_exp2f(x);
#else
    return exp2f(x);
#endif
}

// load 8 consecutive fp32, scale, convert to packed f16 MFMA fragment
__device__ __forceinline__ half8 load_w8s(const float* p, float s) {
    const float4 a = ((const float4*)p)[0];
    const float4 b = ((const float4*)p)[1];
    half8 r;
    r[0] = (_Float16)(s * a.x); r[1] = (_Float16)(s * a.y);
    r[2] = (_Float16)(s * a.z); r[3] = (_Float16)(s * a.w);
    r[4] = (_Float16)(s * b.x); r[5] = (_Float16)(s * b.y);
    r[6] = (_Float16)(s * b.z); r[7] = (_Float16)(s * b.w);
    return r;
}

// R21: FUSED TWO-SET WORKGROUP. R17 (best, 272us; operand-swapped MFMA,
// row-replicated A, in-register preacts, 1 triple/lane) has tick 636cy
// that is NOT issue-bound (worst SIMD ~291cy MFMA) -- it's chain latency
// (barrier + ds_read ~120 + MFMA + gate ~80 + write) + skew. Four micro
// attempts (bpermute R14, rebalance/partials R18, CH=2 TLP R19, G2
// partials+setprio R20) all regressed. R19's lesson: independent blocks
// drift out of phase and serialize chains. This round: ONE 768-thread
// workgroup carries TWO complete CH=4 sets (8 chains), 12 waves, ONE
// shared barrier -> phase-aligned TLP. Per-chain MFMA work unchanged;
// wid%4 placement gives every SIMD exactly {G1-setA, G1-setB, G2} =
// 6+6+9 = 21 tiles (~407cy issue): the two sets' chains fill each
// other's stalls. Win iff tick < 636cy (floor ~430 issue / ~410 chain).
//   wid 0-3 : GRU1 set A, unit-tile wid
//   wid 4-7 : GRU1 set B, unit-tile wid-4
//   wid 8-11: GRU2 (one step behind), set (wid-8)>>1, tile (wid-8)&1
// Grid = 128 blocks x 8 chains. Weights shared across sets.
// MFMA layouts (m89/m120/R16-verified): A[m=lane&15][k=quad*8+j],
// B[k=quad*8+j][n=lane&15], C/D: col(n)=lane&15, row(m)=quad*4+reg.
// A = h1(t-1) with chain nl>>2 replicated over 4 m-rows -> lane's C rows
// are 4 identical copies of (chain=quad, unit=nl)'s preact; use acc[0].
// R8 parity: at tick t, h1(t-1) in s_h1[(t+1)&1]; GRU2 reads h2(t-2)
// from s_h2[t&1], writes h2(t-1) to s_h2[(t+1)&1]. exp2 gates (R10).
__global__ __launch_bounds__(768, 1)
void gru2_encoder(const float* __restrict__ x,
                  const float* __restrict__ W_ih1,
                  const float* __restrict__ W_hh1,
                  const float* __restrict__ b_ih1,
                  const float* __restrict__ b_hh1,
                  const float* __restrict__ W_ih2,
                  const float* __restrict__ W_hh2,
                  const float* __restrict__ b_ih2,
                  const float* __restrict__ b_hh2,
                  float* __restrict__ out)
{
    const int blk  = blockIdx.x;    // 128 blocks, 8 chains each
    const int tid  = threadIdx.x;   // 768
    const int lane = tid & 63;
    const int wid  = tid >> 6;      // 0..11
    const int nl   = lane & 15;     // MFMA non-k lane index (unit col)
    const int quad = lane >> 4;     // 0..3 (= this lane's gate CHAIN within set)
    const int ac   = nl >> 2;       // chain this lane's A-row replicates
    const int chain0 = blk * (CH * SETS);

    const float SNEG = -1.44269504f;       // -log2(e)
    const float SP2  =  2.88539008f;       // 2*log2(e)

    // [par][set][chain][unit(padded)] -- strides as in R17
    __shared__ __align__(16) _Float16 s_h1[2][SETS][4][80];
    __shared__ __align__(16) _Float16 s_h2[2][SETS][4][48];
    __shared__ __align__(16) _Float16 s_x[TSTEPS][8];   // [t][set*4+chain]

    // ---- one-time staging: 8 chains of x (coalesced along t)
    for (int idx = tid; idx < 8 * TSTEPS; idx += 768) {
        const int m = idx >> 10, t = idx & (TSTEPS - 1);
        s_x[t][m] = (_Float16)x[(size_t)(chain0 + m) * TSTEPS + t];
    }
    {
        _Float16* p1 = &s_h1[0][0][0][0];
        for (int idx = tid; idx < 2 * SETS * 4 * 80; idx += 768) p1[idx] = (_Float16)0.0f;
        _Float16* p2 = &s_h2[0][0][0][0];
        for (int idx = tid; idx < 2 * SETS * 4 * 48; idx += 768) p2[idx] = (_Float16)0.0f;
    }
    __syncthreads();

    if (wid < 8) {
        // ================= GRU1, set st, unit-tile g1t: units g1t*16+nl ========
        const int st  = wid >> 2;            // set 0 (A) / 1 (B)
        const int g1t = wid & 3;             // unit-tile 0..3
        const int un  = g1t * 16 + nl;       // this lane's output unit (n-col)
        // weights as B operand: B[k=quad*8+jj][n=nl] = W_hh1[un][k] (pre-scaled)
        const half8 Br0 = load_w8s(W_hh1 + (size_t)(un)        * 64 + quad * 8,      SNEG);
        const half8 Br1 = load_w8s(W_hh1 + (size_t)(un)        * 64 + 32 + quad * 8, SNEG);
        const half8 Bz0 = load_w8s(W_hh1 + (size_t)(64 + un)   * 64 + quad * 8,      SNEG);
        const half8 Bz1 = load_w8s(W_hh1 + (size_t)(64 + un)   * 64 + 32 + quad * 8, SNEG);
        const half8 Bn0 = load_w8s(W_hh1 + (size_t)(128 + un)  * 64 + quad * 8,      SP2);
        const half8 Bn1 = load_w8s(W_hh1 + (size_t)(128 + un)  * 64 + 32 + quad * 8, SP2);
        // bias depends on unit (col) only -> splat across the 4 C rows
        const float cr = SNEG * (b_ih1[un] + b_hh1[un]);
        const float cz = SNEG * (b_ih1[64 + un] + b_hh1[64 + un]);
        const float cn = SP2 * b_hh1[128 + un];
        const f32x4 Cr = {cr, cr, cr, cr};
        const f32x4 Cz = {cz, cz, cz, cz};
        const f32x4 Cn = {cn, cn, cn, cn};
        // x-path scalars for this lane's unit
        const float twr = SNEG * W_ih1[un];
        const float twz = SNEG * W_ih1[64 + un];
        const float twn = SP2  * W_ih1[128 + un];
        const float tbn = SP2  * b_ih1[128 + un];

        float h1s = 0.0f;   // h1[set=st][chain=quad][unit=un]

        for (int t = 0; t <= TSTEPS; ++t) {
            if (t < TSTEPS) {
                const int pr = (t + 1) & 1;
                // A = h1(t-1), chain replicated over 4 rows: A[m=nl] = h1[st][nl>>2][k]
                const half8 A0 = *(const half8*)&s_h1[pr][st][ac][quad * 8];
                const half8 A1 = *(const half8*)&s_h1[pr][st][ac][32 + quad * 8];
                f32x4 aR = MFMA16(A0, Br0, Cr); aR = MFMA16(A1, Br1, aR);
                f32x4 aZ = MFMA16(A0, Bz0, Cz); aZ = MFMA16(A1, Bz1, aZ);
                f32x4 aN = MFMA16(A0, Bn0, Cn); aN = MFMA16(A1, Bn1, aN);
                // C rows 4*quad..4*quad+3 all equal chain quad -> use reg 0
                const float xv = (float)s_x[t][st * 4 + quad];
                const float ea = fast_exp2(fmaf(twr, xv, aR[0]));   // e^{-ar}
                const float eb = fast_exp2(fmaf(twz, xv, aZ[0]));   // e^{-az}
                const float d1 = 1.0f + ea, d2 = 1.0f + eb;
                const float inv = fast_rcp(d1 * d2);
                const float rg = d2 * inv, zg = d1 * inv;
                const float nx = fmaf(twn, xv, tbn);
                const float ec = fast_exp2(fmaf(rg, aN[0], nx));    // e^{2an}
                const float nn = fmaf(-2.0f, fast_rcp(ec + 1.0f), 1.0f);
                h1s = nn + zg * (h1s - nn);
                s_h1[t & 1][st][quad][un] = (_Float16)h1s;
            }
            __syncthreads();
        }
    } else {
        // ================= GRU2, set st, unit-tile g2t, one step behind ========
        const int st  = (wid - 8) >> 1;      // set 0 (A) / 1 (B)
        const int g2t = (wid - 8) & 1;       // unit-tile 0..1
        const int vn  = g2t * 16 + nl;       // this lane's output unit (n-col)
        const half8 BiR0 = load_w8s(W_ih2 + (size_t)(vn)      * 64 + quad * 8,      SNEG);
        const half8 BiR1 = load_w8s(W_ih2 + (size_t)(vn)      * 64 + 32 + quad * 8, SNEG);
        const half8 BiZ0 = load_w8s(W_ih2 + (size_t)(32 + vn) * 64 + quad * 8,      SNEG);
        const half8 BiZ1 = load_w8s(W_ih2 + (size_t)(32 + vn) * 64 + 32 + quad * 8, SNEG);
        const half8 BiN0 = load_w8s(W_ih2 + (size_t)(64 + vn) * 64 + quad * 8,      SP2);
        const half8 BiN1 = load_w8s(W_ih2 + (size_t)(64 + vn) * 64 + 32 + quad * 8, SP2);
        const half8 BhR  = load_w8s(W_hh2 + (size_t)(vn)      * 32 + quad * 8,      SNEG);
        const half8 BhZ  = load_w8s(W_hh2 + (size_t)(32 + vn) * 32 + quad * 8,      SNEG);
        const half8 BhN  = load_w8s(W_hh2 + (size_t)(64 + vn) * 32 + quad * 8,      SP2);
        const float gr  = SNEG * (b_ih2[vn] + b_hh2[vn]);
        const float gz  = SNEG * (b_ih2[32 + vn] + b_hh2[32 + vn]);
        const float gnx = SP2 * b_ih2[64 + vn];
        const float gnh = SP2 * b_hh2[64 + vn];
        const f32x4 Gr  = {gr, gr, gr, gr};
        const f32x4 Gz  = {gz, gz, gz, gz};
        const f32x4 Gnx = {gnx, gnx, gnx, gnx};
        const f32x4 Gnh = {gnh, gnh, gnh, gnh};

        float h2s = 0.0f;   // h2[set=st][chain=quad][unit=vn]

        for (int t = 0; t <= TSTEPS; ++t) {
            if (t >= 1) {
                const int pA = (t + 1) & 1;            // parity of h1(t-1)
                const half8 A0 = *(const half8*)&s_h1[pA][st][ac][quad * 8];
                const half8 A1 = *(const half8*)&s_h1[pA][st][ac][32 + quad * 8];
                const half8 Ah = *(const half8*)&s_h2[t & 1][st][ac][quad * 8];   // h2(t-2)
                f32x4 aR = MFMA16(A0, BiR0, Gr);  aR = MFMA16(A1, BiR1, aR);
                aR = MFMA16(Ah, BhR, aR);
                f32x4 aZ = MFMA16(A0, BiZ0, Gz);  aZ = MFMA16(A1, BiZ1, aZ);
                aZ = MFMA16(Ah, BhZ, aZ);
                f32x4 aNx = MFMA16(A0, BiN0, Gnx); aNx = MFMA16(A1, BiN1, aNx);
                f32x4 aNh = MFMA16(Ah, BhN, Gnh);
                const float ea = fast_exp2(aR[0]);
                const float eb = fast_exp2(aZ[0]);
                const float d1 = 1.0f + ea, d2 = 1.0f + eb;
                const float inv = fast_rcp(d1 * d2);
                const float rg = d2 * inv, zg = d1 * inv;
                const float ec = fast_exp2(fmaf(rg, aNh[0], aNx[0]));
                const float n2 = fmaf(-2.0f, fast_rcp(ec + 1.0f), 1.0f);
                h2s = n2 + zg * (h2s - n2);
                s_h2[(t + 1) & 1][st][quad][vn] = (_Float16)h2s;   // h2(t-1)
            }
            __syncthreads();
        }

        // lane holds h2 for (set st, chain quad, unit vn): coalesced b32 stores
        out[(size_t)(chain0 + st * 4 + quad) * 32 + vn] = h2s;
    }
}

extern "C" void kernel_launch(void* const* d_in, const int* in_sizes, int n_in,
                              void* d_out, int out_size, void* d_ws, size_t ws_size,
                              hipStream_t stream) {
    const float* x     = (const float*)d_in[0];
    const float* W_ih1 = (const float*)d_in[1];
    const float* W_hh1 = (const float*)d_in[2];
    const float* b_ih1 = (const float*)d_in[3];
    const float* b_hh1 = (const float*)d_in[4];
    const float* W_ih2 = (const float*)d_in[5];
    const float* W_hh2 = (const float*)d_in[6];
    const float* b_ih2 = (const float*)d_in[7];
    const float* b_hh2 = (const float*)d_in[8];
    float* out = (float*)d_out;

    gru2_encoder<<<dim3(1024 / (CH * SETS)), dim3(768), 0, stream>>>(
        x, W_ih1, W_hh1, b_ih1, b_hh1, W_ih2, W_hh2, b_ih2, b_hh2, out);
}

// Round 9
// 324.886 us; speedup vs baseline: 1.2371x; 1.2371x over previous
//
#include <hip/hip_runtime.h>

#define TSTEPS 1024
#define CH 4               // chains per block; replicated 4x across MFMA m-rows

typedef _Float16 half8  __attribute__((ext_vector_type(8)));
typedef float    f32x4  __attribute__((ext_vector_type(4)));

#define MFMA16(A_, B_, C_) __builtin_amdgcn_mfma_f32_16x16x32_f16((A_), (B_), (C_), 0, 0, 0)

__device__ __forceinline__ float fast_rcp(float x) { return __builtin_amdgcn_rcpf(x); }
__device__ __forceinline__ float fast_exp2(float x) {
#if __has_builtin(__builtin_amdgcn_exp2f)
    return __builtin_amdgcn_exp2f(x);
#else
    return exp2f(x);
#endif
}

// load 8 consecutive fp32, scale, convert to packed f16 MFMA fragment
__device__ __forceinline__ half8 load_w8s(const float* p, float s) {
    const float4 a = ((const float4*)p)[0];
    const float4 b = ((const float4*)p)[1];
    half8 r;
    r[0] = (_Float16)(s * a.x); r[1] = (_Float16)(s * a.y);
    r[2] = (_Float16)(s * a.z); r[3] = (_Float16)(s * a.w);
    r[4] = (_Float16)(s * b.x); r[5] = (_Float16)(s * b.y);
    r[6] = (_Float16)(s * b.z); r[7] = (_Float16)(s * b.w);
    return r;
}

// R22 = R17 (best: 272us rocprof; operand-swapped MFMA, row-replicated A,
// in-register preacts, 1 gate-triple/lane, 256 blocks x CH=4, 6 waves,
// 1 barrier/tick) + SERIAL-PATH TRIMS ONLY (no scheduling changes; all
// structural alternatives R14/R15/R16-raw/R18/R19/R20/R21 measured worse):
//  1) SPLIT-RCP sigmoids: r = rcp(1+ea), z = rcp(1+eb) instead of the
//     combined rcp(d1*d2)+2 muls -- removes 2 dependent ops from the
//     r->n->h critical chain (r no longer waits on eb).
//  2) G2 MFMA TREE depth 3->2: (A0->A1 chained) || (Ah parallel, C=0),
//     one scalar add per r/z gate (minimal split; R18/R20's full split
//     of ALL chains was over-aggressive and regressed).
//  3) LOOP PEELING: remove per-tick uniform branches. G1: plain loop
//     t=0..1023 {work; barrier}. G2: leading barrier + loop t=1..1023
//     {work; barrier} + peeled final work(1024). Barrier counts match
//     (1024 each); work(t) sits between B_{t-1} and B_t as before.
// R21 post-mortem: fused 2-set workgroup ticked 850cy (2x work for only
// +34% tick -- TLP overlaps well) but 8 chains/block halves block count;
// wall = ticks x tick, so the 2nd set must be ~free to win. TLP exhausted.
// MFMA layouts (m89/m120/R16-verified): A[m=lane&15][k=quad*8+j],
// B[k=quad*8+j][n=lane&15], C/D: col(n)=lane&15, row(m)=quad*4+reg.
// A = h1(t-1) with chain nl>>2 replicated over 4 m-rows -> lane's C rows
// are 4 identical copies of (chain=quad, unit=nl)'s preact; use acc[0].
// LDS strides 80/48 (uniform 2-way). R8 parity: at tick t, h1(t-1) in
// s_h1[(t+1)&1]; GRU2 reads h2(t-2) from s_h2[t&1], writes h2(t-1) to
// s_h2[(t+1)&1]. exp2 pre-scaled gates (R10).
__global__ __launch_bounds__(384, 1)
void gru2_encoder(const float* __restrict__ x,
                  const float* __restrict__ W_ih1,
                  const float* __restrict__ W_hh1,
                  const float* __restrict__ b_ih1,
                  const float* __restrict__ b_hh1,
                  const float* __restrict__ W_ih2,
                  const float* __restrict__ W_hh2,
                  const float* __restrict__ b_ih2,
                  const float* __restrict__ b_hh2,
                  float* __restrict__ out)
{
    const int blk  = blockIdx.x;    // 256 blocks, CH=4 chains each
    const int tid  = threadIdx.x;   // 384
    const int lane = tid & 63;
    const int wid  = tid >> 6;      // 0..5
    const int nl   = lane & 15;     // MFMA non-k lane index (unit col)
    const int quad = lane >> 4;     // 0..3 (= this lane's gate CHAIN)
    const int ac   = nl >> 2;       // chain this lane's A-row replicates
    const int chain0 = blk * CH;

    const float SNEG = -1.44269504f;       // -log2(e)
    const float SP2  =  2.88539008f;       // 2*log2(e)

    // strides padded for uniform 2-way bank access
    __shared__ __align__(16) _Float16 s_h1[2][4][80];   // [par][chain][unit64 pad80]
    __shared__ __align__(16) _Float16 s_h2[2][4][48];   // [par][chain][unit32 pad48]
    __shared__ __align__(16) _Float16 s_x[TSTEPS][4];   // x f16, [t][chain]

    // ---- one-time staging
    for (int idx = tid; idx < 4 * TSTEPS; idx += 384) {
        const int m = idx >> 10, t = idx & (TSTEPS - 1);
        s_x[t][m] = (_Float16)x[(size_t)(chain0 + m) * TSTEPS + t];
    }
    {
        _Float16* p1 = &s_h1[0][0][0];
        for (int idx = tid; idx < 2 * 4 * 80; idx += 384) p1[idx] = (_Float16)0.0f;
        _Float16* p2 = &s_h2[0][0][0];
        for (int idx = tid; idx < 2 * 4 * 48; idx += 384) p2[idx] = (_Float16)0.0f;
    }
    __syncthreads();

    if (wid < 4) {
        // ================= GRU1, unit-tile wid: units wid*16+nl =================
        const int un = wid * 16 + nl;        // this lane's output unit (n-col)
        // weights as B operand: B[k=quad*8+jj][n=nl] = W_hh1[un][k] (pre-scaled)
        const half8 Br0 = load_w8s(W_hh1 + (size_t)(un)        * 64 + quad * 8,      SNEG);
        const half8 Br1 = load_w8s(W_hh1 + (size_t)(un)        * 64 + 32 + quad * 8, SNEG);
        const half8 Bz0 = load_w8s(W_hh1 + (size_t)(64 + un)   * 64 + quad * 8,      SNEG);
        const half8 Bz1 = load_w8s(W_hh1 + (size_t)(64 + un)   * 64 + 32 + quad * 8, SNEG);
        const half8 Bn0 = load_w8s(W_hh1 + (size_t)(128 + un)  * 64 + quad * 8,      SP2);
        const half8 Bn1 = load_w8s(W_hh1 + (size_t)(128 + un)  * 64 + 32 + quad * 8, SP2);
        // bias depends on unit (col) only -> splat across the 4 C rows
        const float cr = SNEG * (b_ih1[un] + b_hh1[un]);
        const float cz = SNEG * (b_ih1[64 + un] + b_hh1[64 + un]);
        const float cn = SP2 * b_hh1[128 + un];
        const f32x4 Cr = {cr, cr, cr, cr};
        const f32x4 Cz = {cz, cz, cz, cz};
        const f32x4 Cn = {cn, cn, cn, cn};
        // x-path scalars for this lane's unit
        const float twr = SNEG * W_ih1[un];
        const float twz = SNEG * W_ih1[64 + un];
        const float twn = SP2  * W_ih1[128 + un];
        const float tbn = SP2  * b_ih1[128 + un];

        float h1s = 0.0f;   // h1[chain=quad][unit=un]

        for (int t = 0; t < TSTEPS; ++t) {
            const int pr = (t + 1) & 1;
            // A = h1(t-1), chain replicated over 4 rows: A[m=nl] = h1[nl>>2][k]
            const half8 A0 = *(const half8*)&s_h1[pr][ac][quad * 8];
            const half8 A1 = *(const half8*)&s_h1[pr][ac][32 + quad * 8];
            f32x4 aR = MFMA16(A0, Br0, Cr); aR = MFMA16(A1, Br1, aR);
            f32x4 aZ = MFMA16(A0, Bz0, Cz); aZ = MFMA16(A1, Bz1, aZ);
            f32x4 aN = MFMA16(A0, Bn0, Cn); aN = MFMA16(A1, Bn1, aN);
            // C rows 4*quad..4*quad+3 all equal chain quad -> use reg 0
            const float xv = (float)s_x[t][quad];
            const float ea = fast_exp2(fmaf(twr, xv, aR[0]));   // e^{-ar}
            const float eb = fast_exp2(fmaf(twz, xv, aZ[0]));   // e^{-az}
            const float rg = fast_rcp(1.0f + ea);               // sigmoid(ar)
            const float zg = fast_rcp(1.0f + eb);               // sigmoid(az)
            const float nx = fmaf(twn, xv, tbn);
            const float ec = fast_exp2(fmaf(rg, aN[0], nx));    // e^{2an}
            const float nn = fmaf(-2.0f, fast_rcp(ec + 1.0f), 1.0f);
            h1s = nn + zg * (h1s - nn);
            s_h1[t & 1][quad][un] = (_Float16)h1s;
            __syncthreads();
        }
    } else {
        // ================= GRU2, units (wid-4)*16+nl, one step behind ==========
        const int vn = (wid - 4) * 16 + nl;  // this lane's output unit (n-col)
        const half8 BiR0 = load_w8s(W_ih2 + (size_t)(vn)      * 64 + quad * 8,      SNEG);
        const half8 BiR1 = load_w8s(W_ih2 + (size_t)(vn)      * 64 + 32 + quad * 8, SNEG);
        const half8 BiZ0 = load_w8s(W_ih2 + (size_t)(32 + vn) * 64 + quad * 8,      SNEG);
        const half8 BiZ1 = load_w8s(W_ih2 + (size_t)(32 + vn) * 64 + 32 + quad * 8, SNEG);
        const half8 BiN0 = load_w8s(W_ih2 + (size_t)(64 + vn) * 64 + quad * 8,      SP2);
        const half8 BiN1 = load_w8s(W_ih2 + (size_t)(64 + vn) * 64 + 32 + quad * 8, SP2);
        const half8 BhR  = load_w8s(W_hh2 + (size_t)(vn)      * 32 + quad * 8,      SNEG);
        const half8 BhZ  = load_w8s(W_hh2 + (size_t)(32 + vn) * 32 + quad * 8,      SNEG);
        const half8 BhN  = load_w8s(W_hh2 + (size_t)(64 + vn) * 32 + quad * 8,      SP2);
        const float gr  = SNEG * (b_ih2[vn] + b_hh2[vn]);
        const float gz  = SNEG * (b_ih2[32 + vn] + b_hh2[32 + vn]);
        const float gnx = SP2 * b_ih2[64 + vn];
        const float gnh = SP2 * b_hh2[64 + vn];
        const f32x4 Gr  = {gr, gr, gr, gr};
        const f32x4 Gz  = {gz, gz, gz, gz};
        const f32x4 Gnx = {gnx, gnx, gnx, gnx};
        const f32x4 Gnh = {gnh, gnh, gnh, gnh};
        const f32x4 Zf  = {0.0f, 0.0f, 0.0f, 0.0f};

        float h2s = 0.0f;   // h2[chain=quad][unit=vn]

        // G2 work(t), t in [1, TSTEPS]: reads h1(t-1) (after barrier B_{t-1}),
        // h2(t-2); writes h2(t-1) (published by barrier B_t).
#define G2_STEP(t_)                                                            \
        {                                                                      \
            const int pA = ((t_) + 1) & 1;                                     \
            const half8 A0 = *(const half8*)&s_h1[pA][ac][quad * 8];           \
            const half8 A1 = *(const half8*)&s_h1[pA][ac][32 + quad * 8];      \
            const half8 Ah = *(const half8*)&s_h2[(t_) & 1][ac][quad * 8];     \
            f32x4 aR  = MFMA16(A0, BiR0, Gr);                                  \
            const f32x4 aRc = MFMA16(Ah, BhR, Zf);                             \
            aR = MFMA16(A1, BiR1, aR);                                         \
            f32x4 aZ  = MFMA16(A0, BiZ0, Gz);                                  \
            const f32x4 aZc = MFMA16(Ah, BhZ, Zf);                             \
            aZ = MFMA16(A1, BiZ1, aZ);                                         \
            f32x4 aNx = MFMA16(A0, BiN0, Gnx);                                 \
            aNx = MFMA16(A1, BiN1, aNx);                                       \
            const f32x4 aNh = MFMA16(Ah, BhN, Gnh);                            \
            const float pR = aR[0] + aRc[0];                                   \
            const float pZ = aZ[0] + aZc[0];                                   \
            const float ea = fast_exp2(pR);                                    \
            const float eb = fast_exp2(pZ);                                    \
            const float rg = fast_rcp(1.0f + ea);                              \
            const float zg = fast_rcp(1.0f + eb);                              \
            const float ec = fast_exp2(fmaf(rg, aNh[0], aNx[0]));              \
            const float n2 = fmaf(-2.0f, fast_rcp(ec + 1.0f), 1.0f);           \
            h2s = n2 + zg * (h2s - n2);                                        \
            s_h2[((t_) + 1) & 1][quad][vn] = (_Float16)h2s;                    \
        }

        __syncthreads();                       // B_0: h1(0) visible
        for (int t = 1; t < TSTEPS; ++t) {
            G2_STEP(t);
            __syncthreads();                   // B_t
        }
        G2_STEP(TSTEPS);                       // final step, no trailing barrier
#undef G2_STEP

        // lane holds h2 for (chain=quad, unit=vn): coalesced b32 stores
        out[(size_t)(chain0 + quad) * 32 + vn] = h2s;
    }
}

extern "C" void kernel_launch(void* const* d_in, const int* in_sizes, int n_in,
                              void* d_out, int out_size, void* d_ws, size_t ws_size,
                              hipStream_t stream) {
    const float* x     = (const float*)d_in[0];
    const float* W_ih1 = (const float*)d_in[1];
    const float* W_hh1 = (const float*)d_in[2];
    const float* b_ih1 = (const float*)d_in[3];
    const float* b_hh1 = (const float*)d_in[4];
    const float* W_ih2 = (const float*)d_in[5];
    const float* W_hh2 = (const float*)d_in[6];
    const float* b_ih2 = (const float*)d_in[7];
    const float* b_hh2 = (const float*)d_in[8];
    float* out = (float*)d_out;

    gru2_encoder<<<dim3(1024 / CH), dim3(384), 0, stream>>>(
        x, W_ih1, W_hh1, b_ih1, b_hh1, W_ih2, W_hh2, b_ih2, b_hh2, out);
}

// Round 10
// 312.617 us; speedup vs baseline: 1.2856x; 1.0392x over previous
//
#include <hip/hip_runtime.h>

#define TSTEPS 1024
#define CH 4               // chains per block; replicated 4x across MFMA m-rows

typedef _Float16 half8  __attribute__((ext_vector_type(8)));
typedef float    f32x4  __attribute__((ext_vector_type(4)));

#define MFMA16(A_, B_, C_) __builtin_amdgcn_mfma_f32_16x16x32_f16((A_), (B_), (C_), 0, 0, 0)

__device__ __forceinline__ float fast_rcp(float x) { return __builtin_amdgcn_rcpf(x); }
__device__ __forceinline__ float fast_exp2(float x) {
#if __has_builtin(__builtin_amdgcn_exp2f)
    return __builtin_amdgcn_exp2f(x);
#else
    return exp2f(x);
#endif
}

// load 8 consecutive fp32, scale, convert to packed f16 MFMA fragment
__device__ __forceinline__ half8 load_w8s(const float* p, float s) {
    const float4 a = ((const float4*)p)[0];
    const float4 b = ((const float4*)p)[1];
    half8 r;
    r[0] = (_Float16)(s * a.x); r[1] = (_Float16)(s * a.y);
    r[2] = (_Float16)(s * a.z); r[3] = (_Float16)(s * a.w);
    r[4] = (_Float16)(s * b.x); r[5] = (_Float16)(s * b.y);
    r[6] = (_Float16)(s * b.z); r[7] = (_Float16)(s * b.w);
    return r;
}

// R23 = R17 VERBATIM (best: 272us rocprof / 311us bench) + ONE instruction:
// s_setprio(1) on GRU1 waves. Evidence: R20 (setprio on G2) cost +28us ->
// G1 is the tick-limiting wave (starving it extended the tick). The
// inverse was never run: G1's 6-MFMA+gate chain runs uncontended on the
// SIMDs hosting a G1+G2 pair; G2 (~150cy slack in the 636cy tick) fills
// the issue gaps at low priority. Zero structural change; R22's bundled
// trims (290us) and all structural variants (R14/15/16/18/19/20/21)
// measured worse than R17 and are reverted.
// Floor arithmetic: 1025 ticks x ~636cy / 2.4GHz = 271us; tick is the
// latency chain {barrier -> ds_read h1 ~120cy -> MFMA deps -> gate chain
// ~100cy -> ds_write -> barrier}, forced by CH=4 MFMA amortization
// (unit-tiled waves => cross-wave h1 exchange every timestep).
// MFMA layouts (m89/m120/R16-verified): A[m=lane&15][k=quad*8+j],
// B[k=quad*8+j][n=lane&15], C/D: col(n)=lane&15, row(m)=quad*4+reg.
// A = h1(t-1) with chain nl>>2 replicated over 4 m-rows -> lane's C rows
// are 4 identical copies of (chain=quad, unit=nl)'s preact; use acc[0].
// LDS strides 80/48 (uniform 2-way). R8 parity: at tick t, h1(t-1) in
// s_h1[(t+1)&1]; GRU2 reads h2(t-2) from s_h2[t&1], writes h2(t-1) to
// s_h2[(t+1)&1]. exp2 pre-scaled gates (R10).
__global__ __launch_bounds__(384, 1)
void gru2_encoder(const float* __restrict__ x,
                  const float* __restrict__ W_ih1,
                  const float* __restrict__ W_hh1,
                  const float* __restrict__ b_ih1,
                  const float* __restrict__ b_hh1,
                  const float* __restrict__ W_ih2,
                  const float* __restrict__ W_hh2,
                  const float* __restrict__ b_ih2,
                  const float* __restrict__ b_hh2,
                  float* __restrict__ out)
{
    const int blk  = blockIdx.x;    // 256 blocks, CH=4 chains each
    const int tid  = threadIdx.x;   // 384
    const int lane = tid & 63;
    const int wid  = tid >> 6;      // 0..5
    const int nl   = lane & 15;     // MFMA non-k lane index (unit col)
    const int quad = lane >> 4;     // 0..3 (= this lane's gate CHAIN)
    const int ac   = nl >> 2;       // chain this lane's A-row replicates
    const int chain0 = blk * CH;

    const float SNEG = -1.44269504f;       // -log2(e)
    const float SP2  =  2.88539008f;       // 2*log2(e)

    // strides padded for uniform 2-way bank access
    __shared__ __align__(16) _Float16 s_h1[2][4][80];   // [par][chain][unit64 pad80]
    __shared__ __align__(16) _Float16 s_h2[2][4][48];   // [par][chain][unit32 pad48]
    __shared__ __align__(16) _Float16 s_x[TSTEPS][4];   // x f16, [t][chain]

    // ---- one-time staging
    for (int idx = tid; idx < 4 * TSTEPS; idx += 384) {
        const int m = idx >> 10, t = idx & (TSTEPS - 1);
        s_x[t][m] = (_Float16)x[(size_t)(chain0 + m) * TSTEPS + t];
    }
    {
        _Float16* p1 = &s_h1[0][0][0];
        for (int idx = tid; idx < 2 * 4 * 80; idx += 384) p1[idx] = (_Float16)0.0f;
        _Float16* p2 = &s_h2[0][0][0];
        for (int idx = tid; idx < 2 * 4 * 48; idx += 384) p2[idx] = (_Float16)0.0f;
    }
    __syncthreads();

    if (wid < 4) {
        // ================= GRU1, unit-tile wid: units wid*16+nl =================
        __builtin_amdgcn_s_setprio(1);       // G1 is the tick-limiting wave (R20 inverse)
        const int un = wid * 16 + nl;        // this lane's output unit (n-col)
        // weights as B operand: B[k=quad*8+jj][n=nl] = W_hh1[un][k] (pre-scaled)
        const half8 Br0 = load_w8s(W_hh1 + (size_t)(un)        * 64 + quad * 8,      SNEG);
        const half8 Br1 = load_w8s(W_hh1 + (size_t)(un)        * 64 + 32 + quad * 8, SNEG);
        const half8 Bz0 = load_w8s(W_hh1 + (size_t)(64 + un)   * 64 + quad * 8,      SNEG);
        const half8 Bz1 = load_w8s(W_hh1 + (size_t)(64 + un)   * 64 + 32 + quad * 8, SNEG);
        const half8 Bn0 = load_w8s(W_hh1 + (size_t)(128 + un)  * 64 + quad * 8,      SP2);
        const half8 Bn1 = load_w8s(W_hh1 + (size_t)(128 + un)  * 64 + 32 + quad * 8, SP2);
        // bias depends on unit (col) only -> splat across the 4 C rows
        const float cr = SNEG * (b_ih1[un] + b_hh1[un]);
        const float cz = SNEG * (b_ih1[64 + un] + b_hh1[64 + un]);
        const float cn = SP2 * b_hh1[128 + un];
        const f32x4 Cr = {cr, cr, cr, cr};
        const f32x4 Cz = {cz, cz, cz, cz};
        const f32x4 Cn = {cn, cn, cn, cn};
        // x-path scalars for this lane's unit
        const float twr = SNEG * W_ih1[un];
        const float twz = SNEG * W_ih1[64 + un];
        const float twn = SP2  * W_ih1[128 + un];
        const float tbn = SP2  * b_ih1[128 + un];

        float h1s = 0.0f;   // h1[chain=quad][unit=un]

        for (int t = 0; t <= TSTEPS; ++t) {
            if (t < TSTEPS) {
                const int pr = (t + 1) & 1;
                // A = h1(t-1), chain replicated over 4 rows: A[m=nl] = h1[nl>>2][k]
                const half8 A0 = *(const half8*)&s_h1[pr][ac][quad * 8];
                const half8 A1 = *(const half8*)&s_h1[pr][ac][32 + quad * 8];
                f32x4 aR = MFMA16(A0, Br0, Cr); aR = MFMA16(A1, Br1, aR);
                f32x4 aZ = MFMA16(A0, Bz0, Cz); aZ = MFMA16(A1, Bz1, aZ);
                f32x4 aN = MFMA16(A0, Bn0, Cn); aN = MFMA16(A1, Bn1, aN);
                // C rows 4*quad..4*quad+3 all equal chain quad -> use reg 0
                const float xv = (float)s_x[t][quad];
                const float ea = fast_exp2(fmaf(twr, xv, aR[0]));   // e^{-ar}
                const float eb = fast_exp2(fmaf(twz, xv, aZ[0]));   // e^{-az}
                const float d1 = 1.0f + ea, d2 = 1.0f + eb;
                const float inv = fast_rcp(d1 * d2);
                const float rg = d2 * inv, zg = d1 * inv;
                const float nx = fmaf(twn, xv, tbn);
                const float ec = fast_exp2(fmaf(rg, aN[0], nx));    // e^{2an}
                const float nn = fmaf(-2.0f, fast_rcp(ec + 1.0f), 1.0f);
                h1s = nn + zg * (h1s - nn);
                s_h1[t & 1][quad][un] = (_Float16)h1s;
            }
            __syncthreads();
        }
    } else {
        // ================= GRU2, units (wid-4)*16+nl, one step behind ==========
        const int vn = (wid - 4) * 16 + nl;  // this lane's output unit (n-col)
        const half8 BiR0 = load_w8s(W_ih2 + (size_t)(vn)      * 64 + quad * 8,      SNEG);
        const half8 BiR1 = load_w8s(W_ih2 + (size_t)(vn)      * 64 + 32 + quad * 8, SNEG);
        const half8 BiZ0 = load_w8s(W_ih2 + (size_t)(32 + vn) * 64 + quad * 8,      SNEG);
        const half8 BiZ1 = load_w8s(W_ih2 + (size_t)(32 + vn) * 64 + 32 + quad * 8, SNEG);
        const half8 BiN0 = load_w8s(W_ih2 + (size_t)(64 + vn) * 64 + quad * 8,      SP2);
        const half8 BiN1 = load_w8s(W_ih2 + (size_t)(64 + vn) * 64 + 32 + quad * 8, SP2);
        const half8 BhR  = load_w8s(W_hh2 + (size_t)(vn)      * 32 + quad * 8,      SNEG);
        const half8 BhZ  = load_w8s(W_hh2 + (size_t)(32 + vn) * 32 + quad * 8,      SNEG);
        const half8 BhN  = load_w8s(W_hh2 + (size_t)(64 + vn) * 32 + quad * 8,      SP2);
        const float gr  = SNEG * (b_ih2[vn] + b_hh2[vn]);
        const float gz  = SNEG * (b_ih2[32 + vn] + b_hh2[32 + vn]);
        const float gnx = SP2 * b_ih2[64 + vn];
        const float gnh = SP2 * b_hh2[64 + vn];
        const f32x4 Gr  = {gr, gr, gr, gr};
        const f32x4 Gz  = {gz, gz, gz, gz};
        const f32x4 Gnx = {gnx, gnx, gnx, gnx};
        const f32x4 Gnh = {gnh, gnh, gnh, gnh};

        float h2s = 0.0f;   // h2[chain=quad][unit=vn]

        for (int t = 0; t <= TSTEPS; ++t) {
            if (t >= 1) {
                const int pA = (t + 1) & 1;            // parity of h1(t-1)
                const half8 A0 = *(const half8*)&s_h1[pA][ac][quad * 8];
                const half8 A1 = *(const half8*)&s_h1[pA][ac][32 + quad * 8];
                const half8 Ah = *(const half8*)&s_h2[t & 1][ac][quad * 8];   // h2(t-2)
                f32x4 aR = MFMA16(A0, BiR0, Gr);  aR = MFMA16(A1, BiR1, aR);
                aR = MFMA16(Ah, BhR, aR);
                f32x4 aZ = MFMA16(A0, BiZ0, Gz);  aZ = MFMA16(A1, BiZ1, aZ);
                aZ = MFMA16(Ah, BhZ, aZ);
                f32x4 aNx = MFMA16(A0, BiN0, Gnx); aNx = MFMA16(A1, BiN1, aNx);
                f32x4 aNh = MFMA16(Ah, BhN, Gnh);
                const float ea = fast_exp2(aR[0]);
                const float eb = fast_exp2(aZ[0]);
                const float d1 = 1.0f + ea, d2 = 1.0f + eb;
                const float inv = fast_rcp(d1 * d2);
                const float rg = d2 * inv, zg = d1 * inv;
                const float ec = fast_exp2(fmaf(rg, aNh[0], aNx[0]));
                const float n2 = fmaf(-2.0f, fast_rcp(ec + 1.0f), 1.0f);
                h2s = n2 + zg * (h2s - n2);
                s_h2[(t + 1) & 1][quad][vn] = (_Float16)h2s;   // h2(t-1)
            }
            __syncthreads();
        }

        // lane holds h2 for (chain=quad, unit=vn): coalesced b32 stores
        out[(size_t)(chain0 + quad) * 32 + vn] = h2s;
    }
}

extern "C" void kernel_launch(void* const* d_in, const int* in_sizes, int n_in,
                              void* d_out, int out_size, void* d_ws, size_t ws_size,
                              hipStream_t stream) {
    const float* x     = (const float*)d_in[0];
    const float* W_ih1 = (const float*)d_in[1];
    const float* W_hh1 = (const float*)d_in[2];
    const float* b_ih1 = (const float*)d_in[3];
    const float* b_hh1 = (const float*)d_in[4];
    const float* W_ih2 = (const float*)d_in[5];
    const float* W_hh2 = (const float*)d_in[6];
    const float* b_ih2 = (const float*)d_in[7];
    const float* b_hh2 = (const float*)d_in[8];
    float* out = (float*)d_out;

    gru2_encoder<<<dim3(1024 / CH), dim3(384), 0, stream>>>(
        x, W_ih1, W_hh1, b_ih1, b_hh1, W_ih2, W_hh2, b_ih2, b_hh2, out);
}

// Round 11
// 311.174 us; speedup vs baseline: 1.2916x; 1.0046x over previous
//
#include <hip/hip_runtime.h>

#define TSTEPS 1024
#define CH 4               // chains per block; replicated 4x across MFMA m-rows

typedef _Float16 half8  __attribute__((ext_vector_type(8)));
typedef float    f32x4  __attribute__((ext_vector_type(4)));

#define MFMA16(A_, B_, C_) __builtin_amdgcn_mfma_f32_16x16x32_f16((A_), (B_), (C_), 0, 0, 0)

__device__ __forceinline__ float fast_rcp(float x) { return __builtin_amdgcn_rcpf(x); }
__device__ __forceinline__ float fast_exp2(float x) {
#if __has_builtin(__builtin_amdgcn_exp2f)
    return __builtin_amdgcn_exp2f(x);
#else
    return exp2f(x);
#endif
}

// load 8 consecutive fp32, scale, convert to packed f16 MFMA fragment
__device__ __forceinline__ half8 load_w8s(const float* p, float s) {
    const float4 a = ((const float4*)p)[0];
    const float4 b = ((const float4*)p)[1];
    half8 r;
    r[0] = (_Float16)(s * a.x); r[1] = (_Float16)(s * a.y);
    r[2] = (_Float16)(s * a.z); r[3] = (_Float16)(s * a.w);
    r[4] = (_Float16)(s * b.x); r[5] = (_Float16)(s * b.y);
    r[6] = (_Float16)(s * b.z); r[7] = (_Float16)(s * b.w);
    return r;
}

// R24 FINAL = R17 VERBATIM (session best: 272us rocprof / 311.7us bench;
// baseline was 429/472us). Structure: operand-swapped MFMA (A = h with
// chain nl>>2 replicated over 4 m-rows, B = pre-scaled f16 weights),
// in-register preacts (C/D row=quad*4+reg gives each lane 4 identical
// copies of (chain=quad, unit=nl)'s preact -> acc[0]), 1 gate-triple per
// lane, 256 blocks x CH=4 chains, 6 waves, 1 barrier/tick.
// TERMINAL: the tick (~636cy) is a pure dependency-latency floor --
// {barrier drain ~120 -> ds_read A-frag ~120 -> chained MFMA ~80 ->
// serial gate chain ~80 -> cvt+ds_write}, with MfmaUtil 27 / VALUBusy 30
// / HBM 0.1% all far from pipe limits. Bracketed from both sides:
//  - 9 structural variants all measured worse: bpermute redistribution
//    (R14 +25%), wave-merge (R15 +48%), CH=16 swap (R16 +83%), CH=2 TLP
//    (R19 +41%), SIMD rebalance + full partials (R18 +6%), G2 partials +
//    setprio(G2) (R20 +10%), fused 2-set workgroup (R21 +34%), serial
//    trims (R22 +7%), setprio(G1) (R23 neutral).
//  - floor arithmetic: 1025 sequential ticks x 636cy / 2.4GHz = 271us.
// The binding constraint: MFMA m-dim=16 forces {chain-amortization, CU
// coverage, cross-wave h1 exchange} trade; CH=4 is optimal and its
// exchange costs one LDS+barrier round-trip per timestep -- CDNA4 has no
// faster cross-wave mechanism (no partial barriers; bpermute shares the
// DS pipe). GRU recurrence is nonlinear -> no time-parallel scan.
// MFMA layouts (m89/m120/R16-verified): A[m=lane&15][k=quad*8+j],
// B[k=quad*8+j][n=lane&15], C/D: col(n)=lane&15, row(m)=quad*4+reg.
// LDS strides 80/48 (uniform 2-way). R8 parity: at tick t, h1(t-1) in
// s_h1[(t+1)&1]; GRU2 reads h2(t-2) from s_h2[t&1], writes h2(t-1) to
// s_h2[(t+1)&1]. exp2 pre-scaled gates (R10).
__global__ __launch_bounds__(384, 1)
void gru2_encoder(const float* __restrict__ x,
                  const float* __restrict__ W_ih1,
                  const float* __restrict__ W_hh1,
                  const float* __restrict__ b_ih1,
                  const float* __restrict__ b_hh1,
                  const float* __restrict__ W_ih2,
                  const float* __restrict__ W_hh2,
                  const float* __restrict__ b_ih2,
                  const float* __restrict__ b_hh2,
                  float* __restrict__ out)
{
    const int blk  = blockIdx.x;    // 256 blocks, CH=4 chains each
    const int tid  = threadIdx.x;   // 384
    const int lane = tid & 63;
    const int wid  = tid >> 6;      // 0..5
    const int nl   = lane & 15;     // MFMA non-k lane index (unit col)
    const int quad = lane >> 4;     // 0..3 (= this lane's gate CHAIN)
    const int ac   = nl >> 2;       // chain this lane's A-row replicates
    const int chain0 = blk * CH;

    const float SNEG = -1.44269504f;       // -log2(e)
    const float SP2  =  2.88539008f;       // 2*log2(e)

    // strides padded for uniform 2-way bank access
    __shared__ __align__(16) _Float16 s_h1[2][4][80];   // [par][chain][unit64 pad80]
    __shared__ __align__(16) _Float16 s_h2[2][4][48];   // [par][chain][unit32 pad48]
    __shared__ __align__(16) _Float16 s_x[TSTEPS][4];   // x f16, [t][chain]

    // ---- one-time staging
    for (int idx = tid; idx < 4 * TSTEPS; idx += 384) {
        const int m = idx >> 10, t = idx & (TSTEPS - 1);
        s_x[t][m] = (_Float16)x[(size_t)(chain0 + m) * TSTEPS + t];
    }
    {
        _Float16* p1 = &s_h1[0][0][0];
        for (int idx = tid; idx < 2 * 4 * 80; idx += 384) p1[idx] = (_Float16)0.0f;
        _Float16* p2 = &s_h2[0][0][0];
        for (int idx = tid; idx < 2 * 4 * 48; idx += 384) p2[idx] = (_Float16)0.0f;
    }
    __syncthreads();

    if (wid < 4) {
        // ================= GRU1, unit-tile wid: units wid*16+nl =================
        const int un = wid * 16 + nl;        // this lane's output unit (n-col)
        // weights as B operand: B[k=quad*8+jj][n=nl] = W_hh1[un][k] (pre-scaled)
        const half8 Br0 = load_w8s(W_hh1 + (size_t)(un)        * 64 + quad * 8,      SNEG);
        const half8 Br1 = load_w8s(W_hh1 + (size_t)(un)        * 64 + 32 + quad * 8, SNEG);
        const half8 Bz0 = load_w8s(W_hh1 + (size_t)(64 + un)   * 64 + quad * 8,      SNEG);
        const half8 Bz1 = load_w8s(W_hh1 + (size_t)(64 + un)   * 64 + 32 + quad * 8, SNEG);
        const half8 Bn0 = load_w8s(W_hh1 + (size_t)(128 + un)  * 64 + quad * 8,      SP2);
        const half8 Bn1 = load_w8s(W_hh1 + (size_t)(128 + un)  * 64 + 32 + quad * 8, SP2);
        // bias depends on unit (col) only -> splat across the 4 C rows
        const float cr = SNEG * (b_ih1[un] + b_hh1[un]);
        const float cz = SNEG * (b_ih1[64 + un] + b_hh1[64 + un]);
        const float cn = SP2 * b_hh1[128 + un];
        const f32x4 Cr = {cr, cr, cr, cr};
        const f32x4 Cz = {cz, cz, cz, cz};
        const f32x4 Cn = {cn, cn, cn, cn};
        // x-path scalars for this lane's unit
        const float twr = SNEG * W_ih1[un];
        const float twz = SNEG * W_ih1[64 + un];
        const float twn = SP2  * W_ih1[128 + un];
        const float tbn = SP2  * b_ih1[128 + un];

        float h1s = 0.0f;   // h1[chain=quad][unit=un]

        for (int t = 0; t <= TSTEPS; ++t) {
            if (t < TSTEPS) {
                const int pr = (t + 1) & 1;
                // A = h1(t-1), chain replicated over 4 rows: A[m=nl] = h1[nl>>2][k]
                const half8 A0 = *(const half8*)&s_h1[pr][ac][quad * 8];
                const half8 A1 = *(const half8*)&s_h1[pr][ac][32 + quad * 8];
                f32x4 aR = MFMA16(A0, Br0, Cr); aR = MFMA16(A1, Br1, aR);
                f32x4 aZ = MFMA16(A0, Bz0, Cz); aZ = MFMA16(A1, Bz1, aZ);
                f32x4 aN = MFMA16(A0, Bn0, Cn); aN = MFMA16(A1, Bn1, aN);
                // C rows 4*quad..4*quad+3 all equal chain quad -> use reg 0
                const float xv = (float)s_x[t][quad];
                const float ea = fast_exp2(fmaf(twr, xv, aR[0]));   // e^{-ar}
                const float eb = fast_exp2(fmaf(twz, xv, aZ[0]));   // e^{-az}
                const float d1 = 1.0f + ea, d2 = 1.0f + eb;
                const float inv = fast_rcp(d1 * d2);
                const float rg = d2 * inv, zg = d1 * inv;
                const float nx = fmaf(twn, xv, tbn);
                const float ec = fast_exp2(fmaf(rg, aN[0], nx));    // e^{2an}
                const float nn = fmaf(-2.0f, fast_rcp(ec + 1.0f), 1.0f);
                h1s = nn + zg * (h1s - nn);
                s_h1[t & 1][quad][un] = (_Float16)h1s;
            }
            __syncthreads();
        }
    } else {
        // ================= GRU2, units (wid-4)*16+nl, one step behind ==========
        const int vn = (wid - 4) * 16 + nl;  // this lane's output unit (n-col)
        const half8 BiR0 = load_w8s(W_ih2 + (size_t)(vn)      * 64 + quad * 8,      SNEG);
        const half8 BiR1 = load_w8s(W_ih2 + (size_t)(vn)      * 64 + 32 + quad * 8, SNEG);
        const half8 BiZ0 = load_w8s(W_ih2 + (size_t)(32 + vn) * 64 + quad * 8,      SNEG);
        const half8 BiZ1 = load_w8s(W_ih2 + (size_t)(32 + vn) * 64 + 32 + quad * 8, SNEG);
        const half8 BiN0 = load_w8s(W_ih2 + (size_t)(64 + vn) * 64 + quad * 8,      SP2);
        const half8 BiN1 = load_w8s(W_ih2 + (size_t)(64 + vn) * 64 + 32 + quad * 8, SP2);
        const half8 BhR  = load_w8s(W_hh2 + (size_t)(vn)      * 32 + quad * 8,      SNEG);
        const half8 BhZ  = load_w8s(W_hh2 + (size_t)(32 + vn) * 32 + quad * 8,      SNEG);
        const half8 BhN  = load_w8s(W_hh2 + (size_t)(64 + vn) * 32 + quad * 8,      SP2);
        const float gr  = SNEG * (b_ih2[vn] + b_hh2[vn]);
        const float gz  = SNEG * (b_ih2[32 + vn] + b_hh2[32 + vn]);
        const float gnx = SP2 * b_ih2[64 + vn];
        const float gnh = SP2 * b_hh2[64 + vn];
        const f32x4 Gr  = {gr, gr, gr, gr};
        const f32x4 Gz  = {gz, gz, gz, gz};
        const f32x4 Gnx = {gnx, gnx, gnx, gnx};
        const f32x4 Gnh = {gnh, gnh, gnh, gnh};

        float h2s = 0.0f;   // h2[chain=quad][unit=vn]

        for (int t = 0; t <= TSTEPS; ++t) {
            if (t >= 1) {
                const int pA = (t + 1) & 1;            // parity of h1(t-1)
                const half8 A0 = *(const half8*)&s_h1[pA][ac][quad * 8];
                const half8 A1 = *(const half8*)&s_h1[pA][ac][32 + quad * 8];
                const half8 Ah = *(const half8*)&s_h2[t & 1][ac][quad * 8];   // h2(t-2)
                f32x4 aR = MFMA16(A0, BiR0, Gr);  aR = MFMA16(A1, BiR1, aR);
                aR = MFMA16(Ah, BhR, aR);
                f32x4 aZ = MFMA16(A0, BiZ0, Gz);  aZ = MFMA16(A1, BiZ1, aZ);
                aZ = MFMA16(Ah, BhZ, aZ);
                f32x4 aNx = MFMA16(A0, BiN0, Gnx); aNx = MFMA16(A1, BiN1, aNx);
                f32x4 aNh = MFMA16(Ah, BhN, Gnh);
                const float ea = fast_exp2(aR[0]);
                const float eb = fast_exp2(aZ[0]);
                const float d1 = 1.0f + ea, d2 = 1.0f + eb;
                const float inv = fast_rcp(d1 * d2);
                const float rg = d2 * inv, zg = d1 * inv;
                const float ec = fast_exp2(fmaf(rg, aNh[0], aNx[0]));
                const float n2 = fmaf(-2.0f, fast_rcp(ec + 1.0f), 1.0f);
                h2s = n2 + zg * (h2s - n2);
                s_h2[(t + 1) & 1][quad][vn] = (_Float16)h2s;   // h2(t-1)
            }
            __syncthreads();
        }

        // lane holds h2 for (chain=quad, unit=vn): coalesced b32 stores
        out[(size_t)(chain0 + quad) * 32 + vn] = h2s;
    }
}

extern "C" void kernel_launch(void* const* d_in, const int* in_sizes, int n_in,
                              void* d_out, int out_size, void* d_ws, size_t ws_size,
                              hipStream_t stream) {
    const float* x     = (const float*)d_in[0];
    const float* W_ih1 = (const float*)d_in[1];
    const float* W_hh1 = (const float*)d_in[2];
    const float* b_ih1 = (const float*)d_in[3];
    const float* b_hh1 = (const float*)d_in[4];
    const float* W_ih2 = (const float*)d_in[5];
    const float* W_hh2 = (const float*)d_in[6];
    const float* b_ih2 = (const float*)d_in[7];
    const float* b_hh2 = (const float*)d_in[8];
    float* out = (float*)d_out;

    gru2_encoder<<<dim3(1024 / CH), dim3(384), 0, stream>>>(
        x, W_ih1, W_hh1, b_ih1, b_hh1, W_ih2, W_hh2, b_ih2, b_hh2, out);
}